// Round 2
// baseline (1447.500 us; speedup 1.0000x reference)
//
#include <hip/hip_runtime.h>
#include <hip/hip_bf16.h>

#define N_ATOMS   32768
#define N_SPECIES 4
#define N_FEAT    7584
#define HIDDEN    256
#define N_STRUCT  1024
#define APS       8192   // atoms per species

typedef __attribute__((ext_vector_type(8))) short bf16x8;
typedef __attribute__((ext_vector_type(4))) float f32x4;

typedef const __attribute__((address_space(1))) void* gptr_t;
typedef __attribute__((address_space(3))) void* lptr_t;

__device__ __forceinline__ unsigned short f2bf(float x) {
    union { float f; unsigned u; } v; v.f = x;
    unsigned r = v.u + 0x7FFFu + ((v.u >> 16) & 1u);   // RNE
    return (unsigned short)(r >> 16);
}
__device__ __forceinline__ float bf2f(unsigned short h) {
    union { unsigned u; float f; } v; v.u = ((unsigned)h) << 16;
    return v.f;
}

// in: [S][K][N] f32  ->  out: [S][N][K] bf16   (K, N multiples of 32)
__global__ void transpose_cvt(const float* __restrict__ in,
                              unsigned short* __restrict__ out,
                              int K, int N) {
    __shared__ unsigned short sh[32][33];
    const int s  = blockIdx.z;
    const int k0 = blockIdx.x * 32;
    const int n0 = blockIdx.y * 32;
    const int tx = threadIdx.x & 31;
    const int ty = threadIdx.x >> 5;   // 0..7
    const float* ip = in + (size_t)s * K * N;
    unsigned short* op = out + (size_t)s * N * K;
#pragma unroll
    for (int i = 0; i < 4; ++i) {
        int k = ty + 8 * i;
        sh[tx][k] = f2bf(ip[(size_t)(k0 + k) * N + n0 + tx]);
    }
    __syncthreads();
#pragma unroll
    for (int i = 0; i < 4; ++i) {
        int n = ty + 8 * i;
        op[(size_t)(n0 + n) * K + k0 + tx] = sh[n][tx];
    }
}

// B stage: 16 KB tile [256 n-rows][32 k] via global_load_lds dwordx4.
// Lane l of wave w, inst j covers row 16*(4w+j)+(l>>2), k-chunk (l&3)*8 —
// lds dest = wave-uniform base + l*16B (required glds layout).
__device__ __forceinline__ void stage_B(const unsigned short* __restrict__ Wts,
                                        int K, int k0,
                                        unsigned short* BsmBuf, int w, int lane) {
#pragma unroll
    for (int j = 0; j < 4; ++j) {
        const unsigned short* gp =
            Wts + (size_t)(16 * (4 * w + j) + (lane >> 2)) * K + k0 + (lane & 3) * 8;
        __builtin_amdgcn_global_load_lds((gptr_t)gp,
                                         (lptr_t)&BsmBuf[(4 * w + j) * 512],
                                         16, 0, 0);
    }
}

__device__ __forceinline__ void load_A(const float* __restrict__ Af, int K, int k0,
                                       int tid, float4 v[2]) {
#pragma unroll
    for (int r = 0; r < 2; ++r) {
        int f = tid + 256 * r;          // float4 index in 64x32 tile
        int row = f >> 3, c4 = f & 7;
        v[r] = *(const float4*)(Af + (size_t)row * K + k0 + c4 * 4);
    }
}
__device__ __forceinline__ void commit_A(unsigned short* AsmBuf, int tid,
                                         const float4 v[2]) {
#pragma unroll
    for (int r = 0; r < 2; ++r) {
        int f = tid + 256 * r;
        int row = f >> 3, c4 = f & 7;
        ushort4 b;
        b.x = f2bf(v[r].x); b.y = f2bf(v[r].y);
        b.z = f2bf(v[r].z); b.w = f2bf(v[r].w);
        *(ushort4*)(&AsmBuf[row * 48 + c4 * 4]) = b;
    }
}

#define HPAD 264   // H-tile stride: 264*2B = 528B -> bank step 4/row, 2-way (free)

// ---------------------------------------------------------------------------
// K1: layer-1 GEMM + bias + silu -> H1 (bf16) in workspace.
// One block = 64 atoms x full 256 hidden. No Hsm here -> 45 KB LDS ->
// 3 blocks/CU (the m97 occupancy). Species->XCD-pair swizzle so each XCD L2
// holds exactly one 3.9 MB Wt1 slice.
// ---------------------------------------------------------------------------
__global__ __launch_bounds__(256, 3) void layer1_gemm(
    const float* __restrict__ features,
    const unsigned short* __restrict__ Wt1,   // [S][256][N_FEAT] bf16
    const float* __restrict__ b1,
    unsigned short* __restrict__ H) {          // [S*APS][256] bf16
    __shared__ unsigned short Asm[2][64 * 48];
    __shared__ unsigned short Bsm[2][256 * 32];

    const int tid  = threadIdx.x;
    const int w    = tid >> 6;
    const int lane = tid & 63;
    const int lm   = lane & 15;
    const int q    = lane >> 4;
    const int kgl  = q * 8;

    // XCD affinity: bid%8 ~ XCD. Species s lives on XCD pair {2s, 2s+1}.
    const int bid = blockIdx.x;
    const int s   = (bid & 7) >> 1;
    const int m0  = (((bid >> 3) << 1) | (bid & 1)) * 64;   // 0..127 blocks/species

    const float* Af = features + ((size_t)s * APS + m0) * N_FEAT;
    const unsigned short* Wts = Wt1 + (size_t)s * 256 * N_FEAT;

    f32x4 acc[4][4];
#pragma unroll
    for (int i = 0; i < 4; ++i)
#pragma unroll
        for (int j = 0; j < 4; ++j)
#pragma unroll
            for (int e = 0; e < 4; ++e) acc[i][j][e] = 0.0f;

    float4 av[2];
    stage_B(Wts, N_FEAT, 0, Bsm[0], w, lane);
    load_A(Af, N_FEAT, 0, tid, av);
    commit_A(Asm[0], tid, av);

    int buf = 0;
    for (int k0 = 0; k0 < N_FEAT; k0 += 32, buf ^= 1) {
        __syncthreads();   // drains prev glds (vmcnt) + ds_writes (lgkm)
        const bool more = (k0 + 32 < N_FEAT);
        if (more) {
            stage_B(Wts, N_FEAT, k0 + 32, Bsm[buf ^ 1], w, lane);
            load_A(Af, N_FEAT, k0 + 32, tid, av);
        }
        bf16x8 af[4], bfr[4];
#pragma unroll
        for (int mf = 0; mf < 4; ++mf)
            af[mf] = *(const bf16x8*)(&Asm[buf][(mf * 16 + lm) * 48 + kgl]);
#pragma unroll
        for (int nf = 0; nf < 4; ++nf)
            bfr[nf] = *(const bf16x8*)(&Bsm[buf][(w * 64 + nf * 16 + lm) * 32 + kgl]);
#pragma unroll
        for (int mf = 0; mf < 4; ++mf)
#pragma unroll
            for (int nf = 0; nf < 4; ++nf)
                acc[mf][nf] = __builtin_amdgcn_mfma_f32_16x16x32_bf16(
                    af[mf], bfr[nf], acc[mf][nf], 0, 0, 0);
        if (more) commit_A(Asm[buf ^ 1], tid, av);
    }

    // Epilogue: bias + silu -> global H (bf16). Regs only; no barrier needed.
    const float* bp = b1 + s * 256;
    unsigned short* Hp = H + ((size_t)s * APS + m0) * 256;
#pragma unroll
    for (int nf = 0; nf < 4; ++nf) {
        int col = w * 64 + nf * 16 + lm;
        float bv = bp[col];
#pragma unroll
        for (int mf = 0; mf < 4; ++mf)
#pragma unroll
            for (int i = 0; i < 4; ++i) {
                int row = mf * 16 + q * 4 + i;
                float x = acc[mf][nf][i] + bv;
                Hp[(size_t)row * 256 + col] = f2bf(x / (1.0f + __expf(-x)));
            }
    }
}

// ---------------------------------------------------------------------------
// K2: layers 2-4 from H1. One block = 64 atoms. Hsm (in-place across layers)
// + double-buffered Bsm = 66.5 KB -> 2 blocks/CU.
// ---------------------------------------------------------------------------
__global__ __launch_bounds__(256, 2) void mlp_tail(
    const unsigned short* __restrict__ H,     // [S*APS][256] bf16
    const unsigned short* __restrict__ Wt2,   // [S][256][256] bf16
    const float* __restrict__ b2,
    const unsigned short* __restrict__ Wt3,
    const float* __restrict__ b3,
    const float* __restrict__ W4,             // [S][256] f32
    const float* __restrict__ b4,
    const int* __restrict__ sidx,
    float* __restrict__ out) {
    __shared__ unsigned short Hsm[64 * HPAD];
    __shared__ unsigned short Bsm[2][256 * 32];

    const int tid  = threadIdx.x;
    const int w    = tid >> 6;
    const int lane = tid & 63;
    const int lm   = lane & 15;
    const int q    = lane >> 4;
    const int kgl  = q * 8;
    const int s    = blockIdx.x >> 7;
    const int m0   = (blockIdx.x & 127) * 64;

    // Stage H1 tile [64][256] -> Hsm [64][HPAD] (coalesced, conflict-free).
    {
        const unsigned short* Hg = H + ((size_t)s * APS + m0) * 256;
#pragma unroll
        for (int i = 0; i < 8; ++i) {
            int c = tid + (i << 8);          // 0..2047 chunks of 8 shorts
            int row = c >> 5, chunk = c & 31;
            bf16x8 v = *(const bf16x8*)(Hg + (size_t)row * 256 + chunk * 8);
            *(bf16x8*)(&Hsm[row * HPAD + chunk * 8]) = v;
        }
    }

    f32x4 acc[4][4];

    // =================== Layers 2,3: A from Hsm, K=256 =======================
#pragma unroll 1
    for (int layer = 0; layer < 2; ++layer) {
        const unsigned short* Wts =
            (layer == 0 ? Wt2 : Wt3) + (size_t)s * 256 * 256;
        const float* bp = (layer == 0 ? b2 : b3) + s * 256;
#pragma unroll
        for (int i = 0; i < 4; ++i)
#pragma unroll
            for (int j = 0; j < 4; ++j)
#pragma unroll
                for (int e = 0; e < 4; ++e) acc[i][j][e] = 0.0f;

        stage_B(Wts, 256, 0, Bsm[0], w, lane);
        int buf = 0;
        for (int k0 = 0; k0 < 256; k0 += 32, buf ^= 1) {
            __syncthreads();   // glds drained; Hsm staging/epilogue writes visible
            if (k0 + 32 < 256)
                stage_B(Wts, 256, k0 + 32, Bsm[buf ^ 1], w, lane);
            bf16x8 af[4], bfr[4];
#pragma unroll
            for (int mf = 0; mf < 4; ++mf)
                af[mf] = *(const bf16x8*)(&Hsm[(mf * 16 + lm) * HPAD + k0 + kgl]);
#pragma unroll
            for (int nf = 0; nf < 4; ++nf)
                bfr[nf] = *(const bf16x8*)(&Bsm[buf][(w * 64 + nf * 16 + lm) * 32 + kgl]);
#pragma unroll
            for (int mf = 0; mf < 4; ++mf)
#pragma unroll
                for (int nf = 0; nf < 4; ++nf)
                    acc[mf][nf] = __builtin_amdgcn_mfma_f32_16x16x32_bf16(
                        af[mf], bfr[nf], acc[mf][nf], 0, 0, 0);
        }
        __syncthreads();   // all Hsm reads (as A) done before in-place overwrite
#pragma unroll
        for (int nf = 0; nf < 4; ++nf) {
            int col = w * 64 + nf * 16 + lm;
            float bv = bp[col];
#pragma unroll
            for (int mf = 0; mf < 4; ++mf)
#pragma unroll
                for (int i = 0; i < 4; ++i) {
                    int row = mf * 16 + q * 4 + i;
                    float x = acc[mf][nf][i] + bv;
                    Hsm[row * HPAD + col] = f2bf(x / (1.0f + __expf(-x)));
                }
        }
    }

    // ============ Layer 4: e[a] = dot(h3[a], W4[s]) + b4[s]; scatter =========
    __syncthreads();
    {
        const float* W4s = W4 + s * 256;
        const int a_loc = w * 16 + lm;    // 0..63
        float sum = 0.0f;
#pragma unroll
        for (int j8 = 0; j8 < 8; ++j8) {
            bf16x8 hv = *(const bf16x8*)(&Hsm[a_loc * HPAD + q * 64 + j8 * 8]);
            float4 w0 = *(const float4*)(W4s + q * 64 + j8 * 8);
            float4 w1 = *(const float4*)(W4s + q * 64 + j8 * 8 + 4);
            sum += bf2f((unsigned short)hv[0]) * w0.x + bf2f((unsigned short)hv[1]) * w0.y +
                   bf2f((unsigned short)hv[2]) * w0.z + bf2f((unsigned short)hv[3]) * w0.w +
                   bf2f((unsigned short)hv[4]) * w1.x + bf2f((unsigned short)hv[5]) * w1.y +
                   bf2f((unsigned short)hv[6]) * w1.z + bf2f((unsigned short)hv[7]) * w1.w;
        }
        sum += __shfl_xor(sum, 16, 64);
        sum += __shfl_xor(sum, 32, 64);
        if (q == 0) {
            int atom = s * APS + m0 + a_loc;
            atomicAdd(&out[sidx[atom]], sum + b4[s]);
        }
    }
}

// ---------------------------------------------------------------------------
// Fallback: round-0 fused single-kernel (no Hb workspace needed). Used only
// if ws_size is too small for the split path's H1 intermediate.
// ---------------------------------------------------------------------------
__global__ __launch_bounds__(256, 2) void fused_mlp(
    const float* __restrict__ features,
    const unsigned short* __restrict__ Wt1,
    const float* __restrict__ b1,
    const unsigned short* __restrict__ Wt2,
    const float* __restrict__ b2,
    const unsigned short* __restrict__ Wt3,
    const float* __restrict__ b3,
    const float* __restrict__ W4,
    const float* __restrict__ b4,
    const int* __restrict__ sidx,
    float* __restrict__ out) {
    __shared__ unsigned short Asm[2][64 * 48];
    __shared__ unsigned short Bsm[2][256 * 32];
    __shared__ unsigned short Hsm[64 * HPAD];

    const int tid  = threadIdx.x;
    const int w    = tid >> 6;
    const int lane = tid & 63;
    const int lm   = lane & 15;
    const int q    = lane >> 4;
    const int kgl  = q * 8;
    const int s    = blockIdx.x >> 7;
    const int m0   = (blockIdx.x & 127) * 64;

    f32x4 acc[4][4];

    {
        const float* Af = features + ((size_t)s * APS + m0) * N_FEAT;
        const unsigned short* Wts = Wt1 + (size_t)s * 256 * N_FEAT;
#pragma unroll
        for (int i = 0; i < 4; ++i)
#pragma unroll
            for (int j = 0; j < 4; ++j)
#pragma unroll
                for (int e = 0; e < 4; ++e) acc[i][j][e] = 0.0f;

        float4 av[2];
        stage_B(Wts, N_FEAT, 0, Bsm[0], w, lane);
        load_A(Af, N_FEAT, 0, tid, av);
        commit_A(Asm[0], tid, av);

        int buf = 0;
        for (int k0 = 0; k0 < N_FEAT; k0 += 32, buf ^= 1) {
            __syncthreads();
            const bool more = (k0 + 32 < N_FEAT);
            if (more) {
                stage_B(Wts, N_FEAT, k0 + 32, Bsm[buf ^ 1], w, lane);
                load_A(Af, N_FEAT, k0 + 32, tid, av);
            }
            bf16x8 af[4], bfr[4];
#pragma unroll
            for (int mf = 0; mf < 4; ++mf)
                af[mf] = *(const bf16x8*)(&Asm[buf][(mf * 16 + lm) * 48 + kgl]);
#pragma unroll
            for (int nf = 0; nf < 4; ++nf)
                bfr[nf] = *(const bf16x8*)(&Bsm[buf][(w * 64 + nf * 16 + lm) * 32 + kgl]);
#pragma unroll
            for (int mf = 0; mf < 4; ++mf)
#pragma unroll
                for (int nf = 0; nf < 4; ++nf)
                    acc[mf][nf] = __builtin_amdgcn_mfma_f32_16x16x32_bf16(
                        af[mf], bfr[nf], acc[mf][nf], 0, 0, 0);
            if (more) commit_A(Asm[buf ^ 1], tid, av);
        }
        __syncthreads();
        const float* bp = b1 + s * 256;
#pragma unroll
        for (int nf = 0; nf < 4; ++nf) {
            int col = w * 64 + nf * 16 + lm;
            float bv = bp[col];
#pragma unroll
            for (int mf = 0; mf < 4; ++mf)
#pragma unroll
                for (int i = 0; i < 4; ++i) {
                    int row = mf * 16 + q * 4 + i;
                    float x = acc[mf][nf][i] + bv;
                    Hsm[row * HPAD + col] = f2bf(x / (1.0f + __expf(-x)));
                }
        }
    }

#pragma unroll 1
    for (int layer = 0; layer < 2; ++layer) {
        const unsigned short* Wts =
            (layer == 0 ? Wt2 : Wt3) + (size_t)s * 256 * 256;
        const float* bp = (layer == 0 ? b2 : b3) + s * 256;
#pragma unroll
        for (int i = 0; i < 4; ++i)
#pragma unroll
            for (int j = 0; j < 4; ++j)
#pragma unroll
                for (int e = 0; e < 4; ++e) acc[i][j][e] = 0.0f;

        stage_B(Wts, 256, 0, Bsm[0], w, lane);
        int buf = 0;
        for (int k0 = 0; k0 < 256; k0 += 32, buf ^= 1) {
            __syncthreads();
            if (k0 + 32 < 256)
                stage_B(Wts, 256, k0 + 32, Bsm[buf ^ 1], w, lane);
            bf16x8 af[4], bfr[4];
#pragma unroll
            for (int mf = 0; mf < 4; ++mf)
                af[mf] = *(const bf16x8*)(&Hsm[(mf * 16 + lm) * HPAD + k0 + kgl]);
#pragma unroll
            for (int nf = 0; nf < 4; ++nf)
                bfr[nf] = *(const bf16x8*)(&Bsm[buf][(w * 64 + nf * 16 + lm) * 32 + kgl]);
#pragma unroll
            for (int mf = 0; mf < 4; ++mf)
#pragma unroll
                for (int nf = 0; nf < 4; ++nf)
                    acc[mf][nf] = __builtin_amdgcn_mfma_f32_16x16x32_bf16(
                        af[mf], bfr[nf], acc[mf][nf], 0, 0, 0);
        }
        __syncthreads();
#pragma unroll
        for (int nf = 0; nf < 4; ++nf) {
            int col = w * 64 + nf * 16 + lm;
            float bv = bp[col];
#pragma unroll
            for (int mf = 0; mf < 4; ++mf)
#pragma unroll
                for (int i = 0; i < 4; ++i) {
                    int row = mf * 16 + q * 4 + i;
                    float x = acc[mf][nf][i] + bv;
                    Hsm[row * HPAD + col] = f2bf(x / (1.0f + __expf(-x)));
                }
        }
    }

    __syncthreads();
    {
        const float* W4s = W4 + s * 256;
        const int a_loc = w * 16 + lm;
        float sum = 0.0f;
#pragma unroll
        for (int j8 = 0; j8 < 8; ++j8) {
            bf16x8 hv = *(const bf16x8*)(&Hsm[a_loc * HPAD + q * 64 + j8 * 8]);
            float4 w0 = *(const float4*)(W4s + q * 64 + j8 * 8);
            float4 w1 = *(const float4*)(W4s + q * 64 + j8 * 8 + 4);
            sum += bf2f((unsigned short)hv[0]) * w0.x + bf2f((unsigned short)hv[1]) * w0.y +
                   bf2f((unsigned short)hv[2]) * w0.z + bf2f((unsigned short)hv[3]) * w0.w +
                   bf2f((unsigned short)hv[4]) * w1.x + bf2f((unsigned short)hv[5]) * w1.y +
                   bf2f((unsigned short)hv[6]) * w1.z + bf2f((unsigned short)hv[7]) * w1.w;
        }
        sum += __shfl_xor(sum, 16, 64);
        sum += __shfl_xor(sum, 32, 64);
        if (q == 0) {
            int atom = s * APS + m0 + a_loc;
            atomicAdd(&out[sidx[atom]], sum + b4[s]);
        }
    }
}

extern "C" void kernel_launch(void* const* d_in, const int* in_sizes, int n_in,
                              void* d_out, int out_size, void* d_ws, size_t ws_size,
                              hipStream_t stream) {
    const float* features = (const float*)d_in[0];
    const int*   sidx     = (const int*)d_in[1];
    // d_in[2] = n_structures scalar (== N_STRUCT)
    const float* W1 = (const float*)d_in[3];
    const float* b1 = (const float*)d_in[4];
    const float* W2 = (const float*)d_in[5];
    const float* b2 = (const float*)d_in[6];
    const float* W3 = (const float*)d_in[7];
    const float* b3 = (const float*)d_in[8];
    const float* W4 = (const float*)d_in[9];
    const float* b4 = (const float*)d_in[10];
    float* out = (float*)d_out;

    const size_t wt1_b = (size_t)N_SPECIES * HIDDEN * N_FEAT * 2;
    const size_t wt2_b = (size_t)N_SPECIES * HIDDEN * HIDDEN * 2;
    const size_t hb_b  = (size_t)N_ATOMS * HIDDEN * 2;
    const size_t need_split = wt1_b + 2 * wt2_b + hb_b;

    char* ws = (char*)d_ws;
    unsigned short* Wt1 = (unsigned short*)ws; ws += wt1_b;
    unsigned short* Wt2 = (unsigned short*)ws; ws += wt2_b;
    unsigned short* Wt3 = (unsigned short*)ws; ws += wt2_b;
    unsigned short* Hb  = (unsigned short*)ws; ws += hb_b;

    hipMemsetAsync(d_out, 0, N_STRUCT * sizeof(float), stream);

    transpose_cvt<<<dim3(N_FEAT / 32, HIDDEN / 32, N_SPECIES), 256, 0, stream>>>(W1, Wt1, N_FEAT, HIDDEN);
    transpose_cvt<<<dim3(HIDDEN / 32, HIDDEN / 32, N_SPECIES), 256, 0, stream>>>(W2, Wt2, HIDDEN, HIDDEN);
    transpose_cvt<<<dim3(HIDDEN / 32, HIDDEN / 32, N_SPECIES), 256, 0, stream>>>(W3, Wt3, HIDDEN, HIDDEN);

    if (ws_size >= need_split) {
        layer1_gemm<<<dim3(N_ATOMS / 64), 256, 0, stream>>>(features, Wt1, b1, Hb);
        mlp_tail<<<dim3(N_ATOMS / 64), 256, 0, stream>>>(
            Hb, Wt2, b2, Wt3, b3, W4, b4, sidx, out);
    } else {
        fused_mlp<<<dim3(N_ATOMS / 64), 256, 0, stream>>>(
            features, Wt1, b1, Wt2, b2, Wt3, b3, W4, b4, sidx, out);
    }
}